// Round 18
// baseline (70.329 us; speedup 1.0000x reference)
//
#include <hip/hip_runtime.h>
#include <math.h>

#define TOTAL 2560
#define NEG_BIG (-1e30f)
#define LOG2E_8 0.18033688011112042f   // 0.125 * log2(e)

typedef __bf16 bf16x8 __attribute__((ext_vector_type(8)));
typedef float f32x4 __attribute__((ext_vector_type(4)));
typedef unsigned short ushort8v __attribute__((ext_vector_type(8)));
typedef unsigned short ushort4v __attribute__((ext_vector_type(4)));

__device__ inline unsigned short f2bf(float f) {
    unsigned u = __builtin_bit_cast(unsigned, f);
    u += 0x7fff + ((u >> 16) & 1);
    return (unsigned short)(u >> 16);
}

__device__ inline void gload16(const void* g, void* l) {
    __builtin_amdgcn_global_load_lds(
        (const __attribute__((address_space(1))) void*)g,
        (__attribute__((address_space(3))) void*)l, 16, 0, 0);
}

// ---------------- fused positional encoding + bf16 casts (proven) -------------
__global__ __launch_bounds__(256) void pos_cast_kernel(
    const float* __restrict__ coords,
    const float* __restrict__ pos_w,
    const float* __restrict__ pos_b,
    const float* __restrict__ f,  const float* __restrict__ qw, const float* __restrict__ pw,
    float* __restrict__ pos_out,
    unsigned short* __restrict__ fb, unsigned short* __restrict__ qwb, unsigned short* __restrict__ pwb)
{
    const int bx = blockIdx.x;
    if (bx < 640) {
        __shared__ float enc[4][100];
        const int wv   = threadIdx.x >> 6;
        const int lane = threadIdx.x & 63;
        const int p = bx * 4 + wv;
        const float c0 = coords[p * 3 + 0];
        const float c1 = coords[p * 3 + 1];
        const float c2 = coords[p * 3 + 2];
        for (int i = lane; i < 99; i += 64) {
            float v;
            if (i < 96) {
                const int d = i >> 5;
                const int j = i & 31;
                const float cv = (d == 0) ? c0 : ((d == 1) ? c1 : c2);
                const float freq = exp2f((float)(j & 15)) * 3.14159265358979323846f;
                const float sc = cv * freq;
                v = (j < 16) ? sinf(sc) : cosf(sc);
            } else {
                v = (i == 96) ? c0 : ((i == 97) ? c1 : c2);
            }
            enc[wv][i] = v;
        }
        float acc = pos_b[lane];
        const float* w = pos_w + lane * 99;
        for (int i = 0; i < 99; ++i) acc = fmaf(enc[wv][i], w[i], acc);
        pos_out[p * 64 + lane] = acc;
    } else {
        const int s = (bx - 640) * 256 + threadIdx.x;
        const float* src; unsigned short* dst; int ls;
        if (s < 163840)      { src = f;  dst = fb;  ls = s; }
        else if (s < 262144) { src = qw; dst = qwb; ls = s - 163840; }
        else                 { src = pw; dst = pwb; ls = s - 262144; }
        const float4 x0 = *(const float4*)(src + ls * 8);
        const float4 x1 = *(const float4*)(src + ls * 8 + 4);
        ushort8v o;
        o[0] = f2bf(x0.x); o[1] = f2bf(x0.y); o[2] = f2bf(x0.z); o[3] = f2bf(x0.w);
        o[4] = f2bf(x1.x); o[5] = f2bf(x1.y); o[6] = f2bf(x1.z); o[7] = f2bf(x1.w);
        *(ushort8v*)(dst + ls * 8) = o;
    }
}

// ---------------- QKV GEMM: bf16 MFMA, 64x64 tile, gload_lds dbuf (proven) ----
__global__ __launch_bounds__(256) void qkv_mfma_kernel(
    const unsigned short* __restrict__ A,
    const unsigned short* __restrict__ Bm,
    const float* __restrict__ pos,
    unsigned short* __restrict__ q_ws,
    unsigned short* __restrict__ k_ws,
    unsigned short* __restrict__ vt_ws)
{
    __shared__ unsigned short Abuf[2][64 * 64];
    __shared__ unsigned short Bbuf[2][64 * 64];
    const int m0 = blockIdx.x * 64;
    const int n0 = blockIdx.y * 64;
    const int t = threadIdx.x;
    const int w = t >> 6, lane = t & 63;
    const int wr = w >> 1, wc = w & 1;
    const int c = lane & 15, g = lane >> 4;

    auto STAGE = [&](int kt, int cur) {
#pragma unroll
        for (int i = 0; i < 2; ++i) {
            const int off = w * 2048 + i * 1024;
            const int ba  = off + lane * 16;
            const int row = ba >> 7;
            const int slot = (ba & 127) >> 4;
            gload16(A  + (m0 + row) * 512 + kt * 64 + ((slot ^ (row & 7)) * 8),
                    (char*)&Abuf[cur][0] + off);
            gload16(Bm + (n0 + row) * 512 + kt * 64 + ((slot ^ (row & 7)) * 8),
                    (char*)&Bbuf[cur][0] + off);
        }
    };

    f32x4 acc[2][2];
#pragma unroll
    for (int mi = 0; mi < 2; ++mi)
#pragma unroll
        for (int ni = 0; ni < 2; ++ni) acc[mi][ni] = (f32x4){0.f, 0.f, 0.f, 0.f};

    STAGE(0, 0);
    int cur = 0;
    for (int kt = 0; kt < 8; ++kt) {
        __syncthreads();
        if (kt + 1 < 8) STAGE(kt + 1, cur ^ 1);
#pragma unroll
        for (int kk = 0; kk < 2; ++kk) {
            bf16x8 af[2], bfr[2];
#pragma unroll
            for (int mi = 0; mi < 2; ++mi) {
                const int row = wr * 32 + mi * 16 + c;
                af[mi] = *(const bf16x8*)&Abuf[cur][row * 64 + ((g + 4 * kk) ^ (row & 7)) * 8];
            }
#pragma unroll
            for (int ni = 0; ni < 2; ++ni) {
                const int row = wc * 32 + ni * 16 + c;
                bfr[ni] = *(const bf16x8*)&Bbuf[cur][row * 64 + ((g + 4 * kk) ^ (row & 7)) * 8];
            }
#pragma unroll
            for (int mi = 0; mi < 2; ++mi)
#pragma unroll
                for (int ni = 0; ni < 2; ++ni)
                    acc[mi][ni] = __builtin_amdgcn_mfma_f32_16x16x32_bf16(af[mi], bfr[ni], acc[mi][ni], 0, 0, 0);
        }
        cur ^= 1;
    }

    const int which = n0 >> 9;
    const int h = (n0 >> 6) & 7;
#pragma unroll
    for (int mi = 0; mi < 2; ++mi)
#pragma unroll
        for (int ni = 0; ni < 2; ++ni) {
            const int dd = wc * 32 + ni * 16 + c;
            const int p0 = m0 + wr * 32 + mi * 16 + 4 * g;
            if (which == 2) {
                ushort4v o4;
#pragma unroll
                for (int r = 0; r < 4; ++r) o4[r] = f2bf(acc[mi][ni][r]);
                *(ushort4v*)(vt_ws + (h * 64 + dd) * TOTAL + p0) = o4;
            } else {
#pragma unroll
                for (int r = 0; r < 4; ++r) {
                    const int p = p0 + r;
                    const float v = acc[mi][ni][r] + pos[p * 64 + dd];
                    const int idx = (h * TOTAL + p) * 64 + dd;
                    if (which == 0) q_ws[idx] = f2bf(v);
                    else            k_ws[idx] = f2bf(v);
                }
            }
        }
}

// ---------------- flash attention: KVBLK=256, FULL dbuf, ONE barrier/tile -----
// K dbuf 64K + V dbuf 64K + swizzled P 32K = exactly 160 KiB LDS.
// Per tile: barA (buf[cur] ready, prior reads retired) -> STAGE K/V(t+1 -> cur^1)
// -> QK[cur] -> softmax(defer-max) -> P write (XOR-swz) -> PV[cur]. h=bx&7 XCD-local.
__global__ __launch_bounds__(256) void attn_kernel(
    const unsigned short* __restrict__ q_ws,
    const unsigned short* __restrict__ k_ws,
    const unsigned short* __restrict__ vt_ws,
    unsigned short* __restrict__ y)
{
    const int bx = blockIdx.x;
    const int h  = bx & 7;
    const int qt = bx >> 3;

    const int t    = threadIdx.x;
    const int w    = t >> 6;
    const int lane = t & 63;
    const int g    = lane >> 4;
    const int c    = lane & 15;
    const int c7   = c & 7;
    const int pswz = c7 << 1;                      // P-group XOR (bits 1..3)

    __shared__ unsigned short Kbuf[2][256 * 64];   // [key][d], swizzled slots
    __shared__ unsigned short Vbuf[2][64 * 256];   // [d][key], swizzled slots
    __shared__ unsigned short P_lds[64 * 256];     // [q][key], XOR-swizzled groups

    const int nphase = (qt < 8) ? 2 : 1;
    int cur = 0;

    for (int phase = 0; phase < nphase; ++phase) {
        const int base = phase ? 0 : 512;
        const int nkt  = phase ? 2 : 8;            // 256-key tiles
        const int kt0  = (!phase && qt < 8) ? 2 : 0;
        const float extra = phase ? 1536.0f : 0.0f;

        const unsigned short* Kg = k_ws + (h * TOTAL + base) * 64;
        const unsigned short* Vg = vt_ws + h * 64 * TOTAL + base;

        const unsigned short* Qrow = q_ws + ((h * TOTAL) + base + qt * 64 + 16 * w + c) * 64;
        const bf16x8 qa0 = *(const bf16x8*)(Qrow + 8 * g);
        const bf16x8 qa1 = *(const bf16x8*)(Qrow + 8 * g + 32);

        float m_old = NEG_BIG, l_old = 0.f;        // stats for q = 16w + c
        f32x4 o_acc[4];
#pragma unroll
        for (int n = 0; n < 4; ++n) o_acc[n] = (f32x4){0.f, 0.f, 0.f, 0.f};

        auto STAGE_K = [&](int kt, int kb) {
#pragma unroll
            for (int i = 0; i < 8; ++i) {
                const int off = w * 8192 + i * 1024;
                const int ba  = off + lane * 16;
                const int row = ba >> 7;
                const int slot = (ba & 127) >> 4;
                gload16(Kg + (kt * 256 + row) * 64 + ((slot ^ (row & 7)) * 8),
                        (char*)&Kbuf[kb][0] + off);
            }
        };
        auto STAGE_V = [&](int kt, int vb) {
#pragma unroll
            for (int i = 0; i < 8; ++i) {
                const int off = w * 8192 + i * 1024;
                const int ba  = off + lane * 16;
                const int dd  = ba >> 9;
                const int slot = (ba & 511) >> 4;
                gload16(Vg + dd * TOTAL + kt * 256 + ((slot ^ (dd & 7)) * 8),
                        (char*)&Vbuf[vb][0] + off);
            }
        };

        if (phase) __syncthreads();    // prior phase's LDS reads retired before restage
        STAGE_K(kt0, cur);
        STAGE_V(kt0, cur);

        for (int kt = kt0; kt < nkt; ++kt) {
            __syncthreads();           // barA: buf[cur] staged; buf[cur^1] readers retired
            if (kt + 1 < nkt) {        // full-tile latency cover into the other buffer
                STAGE_K(kt + 1, cur ^ 1);
                STAGE_V(kt + 1, cur ^ 1);
            }

            // QK: s_acc[n][r] = S[q=16w+c][k=16n+4g+r], n = 0..15
            f32x4 s_acc[16];
#pragma unroll
            for (int n = 0; n < 16; ++n) {
                const int row = 16 * n + c;
                const bf16x8 kb0 = *(const bf16x8*)&Kbuf[cur][row * 64 + ((g + 0) ^ c7) * 8];
                const bf16x8 kb1 = *(const bf16x8*)&Kbuf[cur][row * 64 + ((g + 4) ^ c7) * 8];
                f32x4 a = __builtin_amdgcn_mfma_f32_16x16x32_bf16(kb0, qa0, (f32x4){0.f,0.f,0.f,0.f}, 0, 0, 0);
                s_acc[n] = __builtin_amdgcn_mfma_f32_16x16x32_bf16(kb1, qa1, a, 0, 0, 0);
            }

            // softmax (exp2-domain) with defer-max (T13, THR=8)
            f32x4 m4 = s_acc[0];
#pragma unroll
            for (int n = 1; n < 16; ++n)
#pragma unroll
                for (int r = 0; r < 4; ++r) m4[r] = fmaxf(m4[r], s_acc[n][r]);
            float tm = fmaxf(fmaxf(m4[0], m4[1]), fmaxf(m4[2], m4[3])) * LOG2E_8;
            tm = fmaxf(tm, __shfl_xor(tm, 16));
            tm = fmaxf(tm, __shfl_xor(tm, 32));
            if (!__all(tm <= m_old + 8.0f)) {
                const float m_new = fmaxf(m_old, tm);
                const float corr = exp2f(m_old - m_new);
                float corr_r[4];
#pragma unroll
                for (int r = 0; r < 4; ++r) corr_r[r] = __shfl(corr, 4 * g + r);
#pragma unroll
                for (int n = 0; n < 4; ++n)
#pragma unroll
                    for (int r = 0; r < 4; ++r) o_acc[n][r] *= corr_r[r];
                l_old *= corr;
                m_old = m_new;
            }
            float rs = 0.f;
#pragma unroll
            for (int n = 0; n < 16; ++n)
#pragma unroll
                for (int r = 0; r < 4; ++r) {
                    const float pv = exp2f(fmaf(s_acc[n][r], LOG2E_8, -m_old));
                    s_acc[n][r] = pv;
                    rs += pv;
                }
            rs += __shfl_xor(rs, 16);
            rs += __shfl_xor(rs, 32);
            l_old += rs;

            // P write: keys 16n+4g -> linear 8B-group 4n+g, stored at group^(c7<<1)
            const int prow = (16 * w + c) * 256;
#pragma unroll
            for (int n = 0; n < 16; ++n) {
                ushort4v pk;
#pragma unroll
                for (int r = 0; r < 4; ++r) pk[r] = f2bf(s_acc[n][r]);
                *(ushort4v*)&P_lds[prow + ((4 * n + g) ^ pswz) * 4] = pk;
            }

            // PV: pa reads 16B = even groups {2g+8kk, +1}; swizzle keeps contiguity
#pragma unroll
            for (int kk = 0; kk < 8; ++kk) {
                const bf16x8 pa = *(const bf16x8*)&P_lds[prow + ((2 * g + 8 * kk) ^ pswz) * 4];
                const int vslot = (g + 4 * kk) ^ c7;
#pragma unroll
                for (int n = 0; n < 4; ++n) {
                    const bf16x8 vb = *(const bf16x8*)&Vbuf[cur][(16 * n + c) * 256 + vslot * 8];
                    o_acc[n] = __builtin_amdgcn_mfma_f32_16x16x32_bf16(pa, vb, o_acc[n], 0, 0, 0);
                }
            }
            cur ^= 1;
        }

        float inv_own;
        if (extra > 0.f) {
            const float mn  = fmaxf(m_old, 0.f);
            const float ccf = exp2f(m_old - mn);
            const float l   = l_old * ccf + extra * exp2f(-mn);
            inv_own = ccf / l;
        } else {
            inv_own = 1.0f / l_old;
        }
        float inv_r[4];
#pragma unroll
        for (int r = 0; r < 4; ++r) inv_r[r] = __shfl(inv_own, 4 * g + r);
        unsigned short* yb = y + (base + qt * 64 + 16 * w) * 512 + h * 64;
#pragma unroll
        for (int n = 0; n < 4; ++n)
#pragma unroll
            for (int r = 0; r < 4; ++r)
                yb[(4 * g + r) * 512 + 16 * n + c] = f2bf(o_acc[n][r] * inv_r[r]);
    }
}

// ---------------- output projection: bf16 MFMA, 64x64 tile (proven) -----------
__global__ __launch_bounds__(256) void proj_mfma_kernel(
    const unsigned short* __restrict__ A,    // y_bf [2560][512]
    const unsigned short* __restrict__ Bm,   // projw_bf [512][512]
    const float* __restrict__ bias,
    float* __restrict__ out)
{
    __shared__ unsigned short Abuf[2][64 * 64];
    __shared__ unsigned short Bbuf[2][64 * 64];
    const int m0 = blockIdx.x * 64;
    const int n0 = blockIdx.y * 64;
    const int t = threadIdx.x;
    const int w = t >> 6, lane = t & 63;
    const int wr = w >> 1, wc = w & 1;
    const int c = lane & 15, g = lane >> 4;

    auto STAGE = [&](int kt, int cur) {
#pragma unroll
        for (int i = 0; i < 2; ++i) {
            const int off = w * 2048 + i * 1024;
            const int ba  = off + lane * 16;
            const int row = ba >> 7;
            const int slot = (ba & 127) >> 4;
            gload16(A  + (m0 + row) * 512 + kt * 64 + ((slot ^ (row & 7)) * 8),
                    (char*)&Abuf[cur][0] + off);
            gload16(Bm + (n0 + row) * 512 + kt * 64 + ((slot ^ (row & 7)) * 8),
                    (char*)&Bbuf[cur][0] + off);
        }
    };

    f32x4 acc[2][2];
#pragma unroll
    for (int mi = 0; mi < 2; ++mi)
#pragma unroll
        for (int ni = 0; ni < 2; ++ni) acc[mi][ni] = (f32x4){0.f, 0.f, 0.f, 0.f};

    STAGE(0, 0);
    int cur = 0;
    for (int kt = 0; kt < 8; ++kt) {
        __syncthreads();
        if (kt + 1 < 8) STAGE(kt + 1, cur ^ 1);
#pragma unroll
        for (int kk = 0; kk < 2; ++kk) {
            bf16x8 af[2], bfr[2];
#pragma unroll
            for (int mi = 0; mi < 2; ++mi) {
                const int row = wr * 32 + mi * 16 + c;
                af[mi] = *(const bf16x8*)&Abuf[cur][row * 64 + ((g + 4 * kk) ^ (row & 7)) * 8];
            }
#pragma unroll
            for (int ni = 0; ni < 2; ++ni) {
                const int row = wc * 32 + ni * 16 + c;
                bfr[ni] = *(const bf16x8*)&Bbuf[cur][row * 64 + ((g + 4 * kk) ^ (row & 7)) * 8];
            }
#pragma unroll
            for (int mi = 0; mi < 2; ++mi)
#pragma unroll
                for (int ni = 0; ni < 2; ++ni)
                    acc[mi][ni] = __builtin_amdgcn_mfma_f32_16x16x32_bf16(af[mi], bfr[ni], acc[mi][ni], 0, 0, 0);
        }
        cur ^= 1;
    }

#pragma unroll
    for (int mi = 0; mi < 2; ++mi)
#pragma unroll
        for (int ni = 0; ni < 2; ++ni) {
            const int col = n0 + wc * 32 + ni * 16 + c;
            const float bv = bias[col];
#pragma unroll
            for (int r = 0; r < 4; ++r) {
                const int p = m0 + wr * 32 + mi * 16 + 4 * g + r;
                out[p * 512 + col] = acc[mi][ni][r] + bv;
            }
        }
}

extern "C" void kernel_launch(void* const* d_in, const int* in_sizes, int n_in,
                              void* d_out, int out_size, void* d_ws, size_t ws_size,
                              hipStream_t stream) {
    const float* features = (const float*)d_in[0];
    const float* coords   = (const float*)d_in[1];
    const float* qkv_w    = (const float*)d_in[2];
    const float* proj_w   = (const float*)d_in[3];
    const float* proj_b   = (const float*)d_in[4];
    const float* pos_w    = (const float*)d_in[5];
    const float* pos_b    = (const float*)d_in[6];
    float* out = (float*)d_out;

    float* pos_ws = (float*)d_ws;                                    // 163840 f32
    unsigned short* feat_bf  = (unsigned short*)(pos_ws + TOTAL * 64);
    unsigned short* qkvw_bf  = feat_bf + 2560 * 512;
    unsigned short* projw_bf = qkvw_bf + 1536 * 512;
    unsigned short* q_ws  = projw_bf + 512 * 512;
    unsigned short* k_ws  = q_ws  + 8 * TOTAL * 64;
    unsigned short* vt_ws = k_ws  + 8 * TOTAL * 64;
    unsigned short* y_bf  = vt_ws + 8 * TOTAL * 64;                  // 2560*512 bf16

    pos_cast_kernel<<<dim3(1792), dim3(256), 0, stream>>>(
        coords, pos_w, pos_b, features, qkv_w, proj_w,
        pos_ws, feat_bf, qkvw_bf, projw_bf);
    qkv_mfma_kernel<<<dim3(40, 24), dim3(256), 0, stream>>>(
        feat_bf, qkvw_bf, pos_ws, q_ws, k_ws, vt_ws);
    attn_kernel<<<dim3(256), dim3(256), 0, stream>>>(q_ws, k_ws, vt_ws, y_bf);
    proj_mfma_kernel<<<dim3(40, 8), dim3(256), 0, stream>>>(
        y_bf, projw_bf, proj_b, out);
}

// Round 19
// 58.027 us; speedup vs baseline: 1.2120x; 1.2120x over previous
//
#include <hip/hip_runtime.h>
#include <math.h>

#define TOTAL 2560
#define NEG_BIG (-1e30f)
#define LOG2E_8 0.18033688011112042f   // 0.125 * log2(e)

typedef __bf16 bf16x8 __attribute__((ext_vector_type(8)));
typedef float f32x4 __attribute__((ext_vector_type(4)));
typedef unsigned short ushort8v __attribute__((ext_vector_type(8)));
typedef unsigned short ushort4v __attribute__((ext_vector_type(4)));

__device__ inline unsigned short f2bf(float f) {
    unsigned u = __builtin_bit_cast(unsigned, f);
    u += 0x7fff + ((u >> 16) & 1);
    return (unsigned short)(u >> 16);
}

__device__ inline void gload16(const void* g, void* l) {
    __builtin_amdgcn_global_load_lds(
        (const __attribute__((address_space(1))) void*)g,
        (__attribute__((address_space(3))) void*)l, 16, 0, 0);
}

// ---------------- fused positional encoding + bf16 casts (proven) -------------
__global__ __launch_bounds__(256) void pos_cast_kernel(
    const float* __restrict__ coords,
    const float* __restrict__ pos_w,
    const float* __restrict__ pos_b,
    const float* __restrict__ f,  const float* __restrict__ qw, const float* __restrict__ pw,
    float* __restrict__ pos_out,
    unsigned short* __restrict__ fb, unsigned short* __restrict__ qwb, unsigned short* __restrict__ pwb)
{
    const int bx = blockIdx.x;
    if (bx < 640) {
        __shared__ float enc[4][100];
        const int wv   = threadIdx.x >> 6;
        const int lane = threadIdx.x & 63;
        const int p = bx * 4 + wv;
        const float c0 = coords[p * 3 + 0];
        const float c1 = coords[p * 3 + 1];
        const float c2 = coords[p * 3 + 2];
        for (int i = lane; i < 99; i += 64) {
            float v;
            if (i < 96) {
                const int d = i >> 5;
                const int j = i & 31;
                const float cv = (d == 0) ? c0 : ((d == 1) ? c1 : c2);
                const float freq = exp2f((float)(j & 15)) * 3.14159265358979323846f;
                const float sc = cv * freq;
                v = (j < 16) ? sinf(sc) : cosf(sc);
            } else {
                v = (i == 96) ? c0 : ((i == 97) ? c1 : c2);
            }
            enc[wv][i] = v;
        }
        float acc = pos_b[lane];
        const float* w = pos_w + lane * 99;
        for (int i = 0; i < 99; ++i) acc = fmaf(enc[wv][i], w[i], acc);
        pos_out[p * 64 + lane] = acc;
    } else {
        const int s = (bx - 640) * 256 + threadIdx.x;
        const float* src; unsigned short* dst; int ls;
        if (s < 163840)      { src = f;  dst = fb;  ls = s; }
        else if (s < 262144) { src = qw; dst = qwb; ls = s - 163840; }
        else                 { src = pw; dst = pwb; ls = s - 262144; }
        const float4 x0 = *(const float4*)(src + ls * 8);
        const float4 x1 = *(const float4*)(src + ls * 8 + 4);
        ushort8v o;
        o[0] = f2bf(x0.x); o[1] = f2bf(x0.y); o[2] = f2bf(x0.z); o[3] = f2bf(x0.w);
        o[4] = f2bf(x1.x); o[5] = f2bf(x1.y); o[6] = f2bf(x1.z); o[7] = f2bf(x1.w);
        *(ushort8v*)(dst + ls * 8) = o;
    }
}

// ---------------- QKV GEMM: bf16 MFMA, 64x64 tile, gload_lds dbuf (proven) ----
__global__ __launch_bounds__(256) void qkv_mfma_kernel(
    const unsigned short* __restrict__ A,
    const unsigned short* __restrict__ Bm,
    const float* __restrict__ pos,
    unsigned short* __restrict__ q_ws,
    unsigned short* __restrict__ k_ws,
    unsigned short* __restrict__ vt_ws)
{
    __shared__ unsigned short Abuf[2][64 * 64];
    __shared__ unsigned short Bbuf[2][64 * 64];
    const int m0 = blockIdx.x * 64;
    const int n0 = blockIdx.y * 64;
    const int t = threadIdx.x;
    const int w = t >> 6, lane = t & 63;
    const int wr = w >> 1, wc = w & 1;
    const int c = lane & 15, g = lane >> 4;

    auto STAGE = [&](int kt, int cur) {
#pragma unroll
        for (int i = 0; i < 2; ++i) {
            const int off = w * 2048 + i * 1024;
            const int ba  = off + lane * 16;
            const int row = ba >> 7;
            const int slot = (ba & 127) >> 4;
            gload16(A  + (m0 + row) * 512 + kt * 64 + ((slot ^ (row & 7)) * 8),
                    (char*)&Abuf[cur][0] + off);
            gload16(Bm + (n0 + row) * 512 + kt * 64 + ((slot ^ (row & 7)) * 8),
                    (char*)&Bbuf[cur][0] + off);
        }
    };

    f32x4 acc[2][2];
#pragma unroll
    for (int mi = 0; mi < 2; ++mi)
#pragma unroll
        for (int ni = 0; ni < 2; ++ni) acc[mi][ni] = (f32x4){0.f, 0.f, 0.f, 0.f};

    STAGE(0, 0);
    int cur = 0;
    for (int kt = 0; kt < 8; ++kt) {
        __syncthreads();
        if (kt + 1 < 8) STAGE(kt + 1, cur ^ 1);
#pragma unroll
        for (int kk = 0; kk < 2; ++kk) {
            bf16x8 af[2], bfr[2];
#pragma unroll
            for (int mi = 0; mi < 2; ++mi) {
                const int row = wr * 32 + mi * 16 + c;
                af[mi] = *(const bf16x8*)&Abuf[cur][row * 64 + ((g + 4 * kk) ^ (row & 7)) * 8];
            }
#pragma unroll
            for (int ni = 0; ni < 2; ++ni) {
                const int row = wc * 32 + ni * 16 + c;
                bfr[ni] = *(const bf16x8*)&Bbuf[cur][row * 64 + ((g + 4 * kk) ^ (row & 7)) * 8];
            }
#pragma unroll
            for (int mi = 0; mi < 2; ++mi)
#pragma unroll
                for (int ni = 0; ni < 2; ++ni)
                    acc[mi][ni] = __builtin_amdgcn_mfma_f32_16x16x32_bf16(af[mi], bfr[ni], acc[mi][ni], 0, 0, 0);
        }
        cur ^= 1;
    }

    const int which = n0 >> 9;
    const int h = (n0 >> 6) & 7;
#pragma unroll
    for (int mi = 0; mi < 2; ++mi)
#pragma unroll
        for (int ni = 0; ni < 2; ++ni) {
            const int dd = wc * 32 + ni * 16 + c;
            const int p0 = m0 + wr * 32 + mi * 16 + 4 * g;
            if (which == 2) {
                ushort4v o4;
#pragma unroll
                for (int r = 0; r < 4; ++r) o4[r] = f2bf(acc[mi][ni][r]);
                *(ushort4v*)(vt_ws + (h * 64 + dd) * TOTAL + p0) = o4;
            } else {
#pragma unroll
                for (int r = 0; r < 4; ++r) {
                    const int p = p0 + r;
                    const float v = acc[mi][ni][r] + pos[p * 64 + dd];
                    const int idx = (h * TOTAL + p) * 64 + dd;
                    if (which == 0) q_ws[idx] = f2bf(v);
                    else            k_ws[idx] = f2bf(v);
                }
            }
        }
}

// ---------------- flash attention: R15 skeleton, 8 waves, intra-block split-K --
// 512 threads. Wave w: row-group wp=w&3 (q rows 16wp..16wp+15), key-half=w>>2
// (keys koff..koff+127 of each 256-key tile). Per tile (R15 order): barA ->
// QK(half) -> barB -> STAGE_K(t+1) -> softmax(half, defer-max) -> P write ->
// STAGE_V(t+1) -> PV(half). End of phase: high halves dump (O,m,l) to Om/Oml
// scratch, barrier, low halves merge (split-K formula) + finalize + write y.
__global__ __launch_bounds__(512) void attn_kernel(
    const unsigned short* __restrict__ q_ws,
    const unsigned short* __restrict__ k_ws,
    const unsigned short* __restrict__ vt_ws,
    unsigned short* __restrict__ y)
{
    const int bx = blockIdx.x;
    const int h  = bx & 7;                 // XCD-local heads
    const int qt = bx >> 3;

    const int t    = threadIdx.x;
    const int w    = t >> 6;               // 0..7
    const int wp   = w & 3;                // row-group
    const int half = w >> 2;               // key half
    const int koff = half * 128;
    const int lane = t & 63;
    const int g    = lane >> 4;
    const int c    = lane & 15;
    const int c7   = c & 7;

    __shared__ unsigned short Kbuf[256 * 64];      // [key][d], swizzled, restaged
    __shared__ unsigned short Vbuf[2][64 * 256];   // [d][key], swizzled, dbuf
    __shared__ unsigned short P_lds[64][264];      // [q][key 0..255], pad 264
    __shared__ float  Om[64 * 64];                 // high-half O dump (f32)
    __shared__ float2 Oml[64];                     // high-half (m,l)

    const int nphase = (qt < 8) ? 2 : 1;
    int cur = 0;

    for (int phase = 0; phase < nphase; ++phase) {
        const int base = phase ? 0 : 512;
        const int nkt  = phase ? 2 : 8;            // 256-key tiles
        const int kt0  = (!phase && qt < 8) ? 2 : 0;
        const float extra = phase ? 1536.0f : 0.0f;

        const unsigned short* Kg = k_ws + (h * TOTAL + base) * 64;
        const unsigned short* Vg = vt_ws + h * 64 * TOTAL + base;

        const unsigned short* Qrow = q_ws + ((h * TOTAL) + base + qt * 64 + 16 * wp + c) * 64;
        const bf16x8 qa0 = *(const bf16x8*)(Qrow + 8 * g);
        const bf16x8 qa1 = *(const bf16x8*)(Qrow + 8 * g + 32);

        float m_old = NEG_BIG, l_old = 0.f;        // stats for q=16wp+c, this key-half
        f32x4 o_acc[4];
#pragma unroll
        for (int n = 0; n < 4; ++n) o_acc[n] = (f32x4){0.f, 0.f, 0.f, 0.f};

        // K tile 32 KB / 8 waves = 4 KB each
        auto STAGE_K = [&](int kt) {
#pragma unroll
            for (int i = 0; i < 4; ++i) {
                const int off = w * 4096 + i * 1024;
                const int ba  = off + lane * 16;
                const int row = ba >> 7;
                const int slot = (ba & 127) >> 4;
                gload16(Kg + (kt * 256 + row) * 64 + ((slot ^ (row & 7)) * 8),
                        (char*)&Kbuf[0] + off);
            }
        };
        // V^T tile 32 KB / 8 waves
        auto STAGE_V = [&](int kt, int vb) {
#pragma unroll
            for (int i = 0; i < 4; ++i) {
                const int off = w * 4096 + i * 1024;
                const int ba  = off + lane * 16;
                const int dd  = ba >> 9;
                const int slot = (ba & 511) >> 4;
                gload16(Vg + dd * TOTAL + kt * 256 + ((slot ^ (dd & 7)) * 8),
                        (char*)&Vbuf[vb][0] + off);
            }
        };

        if (phase) __syncthreads();    // prior phase's LDS reads retired before restage
        STAGE_K(kt0);
        STAGE_V(kt0, cur);

        for (int kt = kt0; kt < nkt; ++kt) {
            __syncthreads();           // barA: K(kt), V[cur] staged

            // QK over this wave's key half: s_acc[n][r] = S[q=16wp+c][k=koff+16n+4g+r]
            f32x4 s_acc[8];
#pragma unroll
            for (int n = 0; n < 8; ++n) {
                const int row = koff + 16 * n + c;
                const bf16x8 kb0 = *(const bf16x8*)&Kbuf[row * 64 + ((g + 0) ^ c7) * 8];
                const bf16x8 kb1 = *(const bf16x8*)&Kbuf[row * 64 + ((g + 4) ^ c7) * 8];
                f32x4 a = __builtin_amdgcn_mfma_f32_16x16x32_bf16(kb0, qa0, (f32x4){0.f,0.f,0.f,0.f}, 0, 0, 0);
                s_acc[n] = __builtin_amdgcn_mfma_f32_16x16x32_bf16(kb1, qa1, a, 0, 0, 0);
            }
            __syncthreads();           // barB: all QK LDS reads retired -> K free
            if (kt + 1 < nkt) STAGE_K(kt + 1);

            // softmax (exp2-domain, defer-max THR=8) over 32 in-reg values
            f32x4 m4 = s_acc[0];
#pragma unroll
            for (int n = 1; n < 8; ++n)
#pragma unroll
                for (int r = 0; r < 4; ++r) m4[r] = fmaxf(m4[r], s_acc[n][r]);
            float tm = fmaxf(fmaxf(m4[0], m4[1]), fmaxf(m4[2], m4[3])) * LOG2E_8;
            tm = fmaxf(tm, __shfl_xor(tm, 16));
            tm = fmaxf(tm, __shfl_xor(tm, 32));
            if (!__all(tm <= m_old + 8.0f)) {
                const float m_new = fmaxf(m_old, tm);
                const float corr = exp2f(m_old - m_new);
                float corr_r[4];
#pragma unroll
                for (int r = 0; r < 4; ++r) corr_r[r] = __shfl(corr, 4 * g + r);
#pragma unroll
                for (int n = 0; n < 4; ++n)
#pragma unroll
                    for (int r = 0; r < 4; ++r) o_acc[n][r] *= corr_r[r];
                l_old *= corr;
                m_old = m_new;
            }
            float rs = 0.f;
#pragma unroll
            for (int n = 0; n < 8; ++n)
#pragma unroll
                for (int r = 0; r < 4; ++r) {
                    const float pv = exp2f(fmaf(s_acc[n][r], LOG2E_8, -m_old));
                    s_acc[n][r] = pv;
                    rs += pv;
                }
            rs += __shfl_xor(rs, 16);
            rs += __shfl_xor(rs, 32);
            l_old += rs;

            // P write (wave-local rows, own key-half columns)
#pragma unroll
            for (int n = 0; n < 8; ++n) {
                ushort4v pk;
#pragma unroll
                for (int r = 0; r < 4; ++r) pk[r] = f2bf(s_acc[n][r]);
                *(ushort4v*)&P_lds[16 * wp + c][koff + 16 * n + 4 * g] = pk;
            }

            if (kt + 1 < nkt) STAGE_V(kt + 1, cur ^ 1);   // overlap with PV

            // PV over this wave's key half (4 k-slices of 32)
#pragma unroll
            for (int kk = 0; kk < 4; ++kk) {
                const bf16x8 pa = *(const bf16x8*)&P_lds[16 * wp + c][koff + 8 * g + 32 * kk];
                const int vgrp = ((koff >> 3) + 4 * kk + g) ^ c7;
#pragma unroll
                for (int n = 0; n < 4; ++n) {
                    const bf16x8 vb = *(const bf16x8*)&Vbuf[cur][(16 * n + c) * 256 + vgrp * 8];
                    o_acc[n] = __builtin_amdgcn_mfma_f32_16x16x32_bf16(pa, vb, o_acc[n], 0, 0, 0);
                }
            }
            cur ^= 1;
        }

        // ---- merge key halves ----
        if (half == 1) {
            const int pr = wp * 16;
#pragma unroll
            for (int n = 0; n < 4; ++n)
#pragma unroll
                for (int r = 0; r < 4; ++r)
                    Om[(pr + 4 * g + r) * 64 + 16 * n + c] = o_acc[n][r];
            if (g == 0) Oml[pr + c] = make_float2(m_old, l_old);
        }
        __syncthreads();
        if (half == 0) {
            const int pr = wp * 16;
            const float2 o2 = Oml[pr + c];
            const float mm = fmaxf(m_old, o2.x);
            const float f0 = exp2f(m_old - mm), f1 = exp2f(o2.x - mm);
            float l = l_old * f0 + o2.y * f1;
            float so = 1.f;
            if (extra > 0.f) {
                const float mn = fmaxf(mm, 0.f);
                const float cc = exp2f(mm - mn);
                l = l * cc + extra * exp2f(-mn);
                so = cc;
            }
            const float inv = so / l;
            const float a0 = f0 * inv, a1 = f1 * inv;
            float a0r[4], a1r[4];
#pragma unroll
            for (int r = 0; r < 4; ++r) {
                a0r[r] = __shfl(a0, 4 * g + r);
                a1r[r] = __shfl(a1, 4 * g + r);
            }
            unsigned short* yb = y + (base + qt * 64 + 16 * wp) * 512 + h * 64;
#pragma unroll
            for (int n = 0; n < 4; ++n)
#pragma unroll
                for (int r = 0; r < 4; ++r) {
                    const float o1v = Om[(pr + 4 * g + r) * 64 + 16 * n + c];
                    yb[(4 * g + r) * 512 + 16 * n + c] =
                        f2bf(o_acc[n][r] * a0r[r] + o1v * a1r[r]);
                }
        }
    }
}

// ---------------- output projection: bf16 MFMA, 64x64 tile (proven) -----------
__global__ __launch_bounds__(256) void proj_mfma_kernel(
    const unsigned short* __restrict__ A,    // y_bf [2560][512]
    const unsigned short* __restrict__ Bm,   // projw_bf [512][512]
    const float* __restrict__ bias,
    float* __restrict__ out)
{
    __shared__ unsigned short Abuf[2][64 * 64];
    __shared__ unsigned short Bbuf[2][64 * 64];
    const int m0 = blockIdx.x * 64;
    const int n0 = blockIdx.y * 64;
    const int t = threadIdx.x;
    const int w = t >> 6, lane = t & 63;
    const int wr = w >> 1, wc = w & 1;
    const int c = lane & 15, g = lane >> 4;

    auto STAGE = [&](int kt, int cur) {
#pragma unroll
        for (int i = 0; i < 2; ++i) {
            const int off = w * 2048 + i * 1024;
            const int ba  = off + lane * 16;
            const int row = ba >> 7;
            const int slot = (ba & 127) >> 4;
            gload16(A  + (m0 + row) * 512 + kt * 64 + ((slot ^ (row & 7)) * 8),
                    (char*)&Abuf[cur][0] + off);
            gload16(Bm + (n0 + row) * 512 + kt * 64 + ((slot ^ (row & 7)) * 8),
                    (char*)&Bbuf[cur][0] + off);
        }
    };

    f32x4 acc[2][2];
#pragma unroll
    for (int mi = 0; mi < 2; ++mi)
#pragma unroll
        for (int ni = 0; ni < 2; ++ni) acc[mi][ni] = (f32x4){0.f, 0.f, 0.f, 0.f};

    STAGE(0, 0);
    int cur = 0;
    for (int kt = 0; kt < 8; ++kt) {
        __syncthreads();
        if (kt + 1 < 8) STAGE(kt + 1, cur ^ 1);
#pragma unroll
        for (int kk = 0; kk < 2; ++kk) {
            bf16x8 af[2], bfr[2];
#pragma unroll
            for (int mi = 0; mi < 2; ++mi) {
                const int row = wr * 32 + mi * 16 + c;
                af[mi] = *(const bf16x8*)&Abuf[cur][row * 64 + ((g + 4 * kk) ^ (row & 7)) * 8];
            }
#pragma unroll
            for (int ni = 0; ni < 2; ++ni) {
                const int row = wc * 32 + ni * 16 + c;
                bfr[ni] = *(const bf16x8*)&Bbuf[cur][row * 64 + ((g + 4 * kk) ^ (row & 7)) * 8];
            }
#pragma unroll
            for (int mi = 0; mi < 2; ++mi)
#pragma unroll
                for (int ni = 0; ni < 2; ++ni)
                    acc[mi][ni] = __builtin_amdgcn_mfma_f32_16x16x32_bf16(af[mi], bfr[ni], acc[mi][ni], 0, 0, 0);
        }
        cur ^= 1;
    }

#pragma unroll
    for (int mi = 0; mi < 2; ++mi)
#pragma unroll
        for (int ni = 0; ni < 2; ++ni) {
            const int col = n0 + wc * 32 + ni * 16 + c;
            const float bv = bias[col];
#pragma unroll
            for (int r = 0; r < 4; ++r) {
                const int p = m0 + wr * 32 + mi * 16 + 4 * g + r;
                out[p * 512 + col] = acc[mi][ni][r] + bv;
            }
        }
}

extern "C" void kernel_launch(void* const* d_in, const int* in_sizes, int n_in,
                              void* d_out, int out_size, void* d_ws, size_t ws_size,
                              hipStream_t stream) {
    const float* features = (const float*)d_in[0];
    const float* coords   = (const float*)d_in[1];
    const float* qkv_w    = (const float*)d_in[2];
    const float* proj_w   = (const float*)d_in[3];
    const float* proj_b   = (const float*)d_in[4];
    const float* pos_w    = (const float*)d_in[5];
    const float* pos_b    = (const float*)d_in[6];
    float* out = (float*)d_out;

    float* pos_ws = (float*)d_ws;                                    // 163840 f32
    unsigned short* feat_bf  = (unsigned short*)(pos_ws + TOTAL * 64);
    unsigned short* qkvw_bf  = feat_bf + 2560 * 512;
    unsigned short* projw_bf = qkvw_bf + 1536 * 512;
    unsigned short* q_ws  = projw_bf + 512 * 512;
    unsigned short* k_ws  = q_ws  + 8 * TOTAL * 64;
    unsigned short* vt_ws = k_ws  + 8 * TOTAL * 64;
    unsigned short* y_bf  = vt_ws + 8 * TOTAL * 64;                  // 2560*512 bf16

    pos_cast_kernel<<<dim3(1792), dim3(256), 0, stream>>>(
        coords, pos_w, pos_b, features, qkv_w, proj_w,
        pos_ws, feat_bf, qkvw_bf, projw_bf);
    qkv_mfma_kernel<<<dim3(40, 24), dim3(256), 0, stream>>>(
        feat_bf, qkvw_bf, pos_ws, q_ws, k_ws, vt_ws);
    attn_kernel<<<dim3(256), dim3(512), 0, stream>>>(q_ws, k_ws, vt_ws, y_bf);
    proj_mfma_kernel<<<dim3(40, 8), dim3(256), 0, stream>>>(
        y_bf, projw_bf, proj_b, out);
}

// Round 20
// 57.953 us; speedup vs baseline: 1.2136x; 1.0013x over previous
//
#include <hip/hip_runtime.h>
#include <math.h>

#define TOTAL 2560
#define NEG_BIG (-1e30f)
#define LOG2E_8 0.18033688011112042f   // 0.125 * log2(e)

typedef __bf16 bf16x8 __attribute__((ext_vector_type(8)));
typedef float f32x4 __attribute__((ext_vector_type(4)));
typedef unsigned short ushort8v __attribute__((ext_vector_type(8)));
typedef unsigned short ushort4v __attribute__((ext_vector_type(4)));

__device__ inline unsigned short f2bf(float f) {
    unsigned u = __builtin_bit_cast(unsigned, f);
    u += 0x7fff + ((u >> 16) & 1);
    return (unsigned short)(u >> 16);
}

__device__ inline void gload16(const void* g, void* l) {
    __builtin_amdgcn_global_load_lds(
        (const __attribute__((address_space(1))) void*)g,
        (__attribute__((address_space(3))) void*)l, 16, 0, 0);
}

// ---------------- fused positional encoding + bf16 casts (proven) -------------
__global__ __launch_bounds__(256) void pos_cast_kernel(
    const float* __restrict__ coords,
    const float* __restrict__ pos_w,
    const float* __restrict__ pos_b,
    const float* __restrict__ f,  const float* __restrict__ qw, const float* __restrict__ pw,
    float* __restrict__ pos_out,
    unsigned short* __restrict__ fb, unsigned short* __restrict__ qwb, unsigned short* __restrict__ pwb)
{
    const int bx = blockIdx.x;
    if (bx < 640) {
        __shared__ float enc[4][100];
        const int wv   = threadIdx.x >> 6;
        const int lane = threadIdx.x & 63;
        const int p = bx * 4 + wv;
        const float c0 = coords[p * 3 + 0];
        const float c1 = coords[p * 3 + 1];
        const float c2 = coords[p * 3 + 2];
        for (int i = lane; i < 99; i += 64) {
            float v;
            if (i < 96) {
                const int d = i >> 5;
                const int j = i & 31;
                const float cv = (d == 0) ? c0 : ((d == 1) ? c1 : c2);
                const float freq = exp2f((float)(j & 15)) * 3.14159265358979323846f;
                const float sc = cv * freq;
                v = (j < 16) ? sinf(sc) : cosf(sc);
            } else {
                v = (i == 96) ? c0 : ((i == 97) ? c1 : c2);
            }
            enc[wv][i] = v;
        }
        float acc = pos_b[lane];
        const float* w = pos_w + lane * 99;
        for (int i = 0; i < 99; ++i) acc = fmaf(enc[wv][i], w[i], acc);
        pos_out[p * 64 + lane] = acc;
    } else {
        const int s = (bx - 640) * 256 + threadIdx.x;
        const float* src; unsigned short* dst; int ls;
        if (s < 163840)      { src = f;  dst = fb;  ls = s; }
        else if (s < 262144) { src = qw; dst = qwb; ls = s - 163840; }
        else                 { src = pw; dst = pwb; ls = s - 262144; }
        const float4 x0 = *(const float4*)(src + ls * 8);
        const float4 x1 = *(const float4*)(src + ls * 8 + 4);
        ushort8v o;
        o[0] = f2bf(x0.x); o[1] = f2bf(x0.y); o[2] = f2bf(x0.z); o[3] = f2bf(x0.w);
        o[4] = f2bf(x1.x); o[5] = f2bf(x1.y); o[6] = f2bf(x1.z); o[7] = f2bf(x1.w);
        *(ushort8v*)(dst + ls * 8) = o;
    }
}

// ---------------- QKV GEMM: bf16 MFMA, 64x64 tile, gload_lds dbuf (proven) ----
__global__ __launch_bounds__(256) void qkv_mfma_kernel(
    const unsigned short* __restrict__ A,
    const unsigned short* __restrict__ Bm,
    const float* __restrict__ pos,
    unsigned short* __restrict__ q_ws,
    unsigned short* __restrict__ k_ws,
    unsigned short* __restrict__ vt_ws)
{
    __shared__ unsigned short Abuf[2][64 * 64];
    __shared__ unsigned short Bbuf[2][64 * 64];
    const int m0 = blockIdx.x * 64;
    const int n0 = blockIdx.y * 64;
    const int t = threadIdx.x;
    const int w = t >> 6, lane = t & 63;
    const int wr = w >> 1, wc = w & 1;
    const int c = lane & 15, g = lane >> 4;

    auto STAGE = [&](int kt, int cur) {
#pragma unroll
        for (int i = 0; i < 2; ++i) {
            const int off = w * 2048 + i * 1024;
            const int ba  = off + lane * 16;
            const int row = ba >> 7;
            const int slot = (ba & 127) >> 4;
            gload16(A  + (m0 + row) * 512 + kt * 64 + ((slot ^ (row & 7)) * 8),
                    (char*)&Abuf[cur][0] + off);
            gload16(Bm + (n0 + row) * 512 + kt * 64 + ((slot ^ (row & 7)) * 8),
                    (char*)&Bbuf[cur][0] + off);
        }
    };

    f32x4 acc[2][2];
#pragma unroll
    for (int mi = 0; mi < 2; ++mi)
#pragma unroll
        for (int ni = 0; ni < 2; ++ni) acc[mi][ni] = (f32x4){0.f, 0.f, 0.f, 0.f};

    STAGE(0, 0);
    int cur = 0;
    for (int kt = 0; kt < 8; ++kt) {
        __syncthreads();
        if (kt + 1 < 8) STAGE(kt + 1, cur ^ 1);
#pragma unroll
        for (int kk = 0; kk < 2; ++kk) {
            bf16x8 af[2], bfr[2];
#pragma unroll
            for (int mi = 0; mi < 2; ++mi) {
                const int row = wr * 32 + mi * 16 + c;
                af[mi] = *(const bf16x8*)&Abuf[cur][row * 64 + ((g + 4 * kk) ^ (row & 7)) * 8];
            }
#pragma unroll
            for (int ni = 0; ni < 2; ++ni) {
                const int row = wc * 32 + ni * 16 + c;
                bfr[ni] = *(const bf16x8*)&Bbuf[cur][row * 64 + ((g + 4 * kk) ^ (row & 7)) * 8];
            }
#pragma unroll
            for (int mi = 0; mi < 2; ++mi)
#pragma unroll
                for (int ni = 0; ni < 2; ++ni)
                    acc[mi][ni] = __builtin_amdgcn_mfma_f32_16x16x32_bf16(af[mi], bfr[ni], acc[mi][ni], 0, 0, 0);
        }
        cur ^= 1;
    }

    const int which = n0 >> 9;
    const int h = (n0 >> 6) & 7;
#pragma unroll
    for (int mi = 0; mi < 2; ++mi)
#pragma unroll
        for (int ni = 0; ni < 2; ++ni) {
            const int dd = wc * 32 + ni * 16 + c;
            const int p0 = m0 + wr * 32 + mi * 16 + 4 * g;
            if (which == 2) {
                ushort4v o4;
#pragma unroll
                for (int r = 0; r < 4; ++r) o4[r] = f2bf(acc[mi][ni][r]);
                *(ushort4v*)(vt_ws + (h * 64 + dd) * TOTAL + p0) = o4;
            } else {
#pragma unroll
                for (int r = 0; r < 4; ++r) {
                    const int p = p0 + r;
                    const float v = acc[mi][ni][r] + pos[p * 64 + dd];
                    const int idx = (h * TOTAL + p) * 64 + dd;
                    if (which == 0) q_ws[idx] = f2bf(v);
                    else            k_ws[idx] = f2bf(v);
                }
            }
        }
}

// ---------------- flash attention: 16 waves, intra-block split-K x4 ------------
// 1024 threads. Wave w: row-group wp=w&3 (q rows 16wp..16wp+15), key-quarter
// qu=w>>2 (keys qu*64..qu*64+63 of each 256-key tile). Per tile: barA -> QK ->
// barB -> STAGE_K(t+1) -> softmax(defer-max) -> P write -> STAGE_V(t+1) -> PV.
// End of phase: barrier; quarters 1-3 dump (O,m,l) to Vbuf-reused f32 scratch;
// barrier; quarter 0 merges (exact 4-way split-K) + finalize + write y.
__global__ __launch_bounds__(1024) void attn_kernel(
    const unsigned short* __restrict__ q_ws,
    const unsigned short* __restrict__ k_ws,
    const unsigned short* __restrict__ vt_ws,
    unsigned short* __restrict__ y)
{
    const int bx = blockIdx.x;
    const int h  = bx & 7;                 // XCD-local heads
    const int qt = bx >> 3;

    const int t    = threadIdx.x;
    const int w    = t >> 6;               // 0..15
    const int wp   = w & 3;                // row-group
    const int qu   = w >> 2;               // key quarter
    const int koff = qu * 64;
    const int lane = t & 63;
    const int g    = lane >> 4;
    const int c    = lane & 15;
    const int c7   = c & 7;

    __shared__ unsigned short Kbuf[256 * 64];      // [key][d], swizzled, restaged
    __shared__ unsigned short Vbuf[2][64 * 256];   // [d][key], swizzled, dbuf (+ merge scratch)
    __shared__ unsigned short P_lds[64][264];      // [q][key], wave-local rows
    __shared__ float2 Oml[3][64];                  // quarters 1..3 (m,l)

    const int nphase = (qt < 8) ? 2 : 1;
    int cur = 0;

    for (int phase = 0; phase < nphase; ++phase) {
        const int base = phase ? 0 : 512;
        const int nkt  = phase ? 2 : 8;            // 256-key tiles
        const int kt0  = (!phase && qt < 8) ? 2 : 0;
        const float extra = phase ? 1536.0f : 0.0f;

        const unsigned short* Kg = k_ws + (h * TOTAL + base) * 64;
        const unsigned short* Vg = vt_ws + h * 64 * TOTAL + base;

        const unsigned short* Qrow = q_ws + ((h * TOTAL) + base + qt * 64 + 16 * wp + c) * 64;
        const bf16x8 qa0 = *(const bf16x8*)(Qrow + 8 * g);
        const bf16x8 qa1 = *(const bf16x8*)(Qrow + 8 * g + 32);

        float m_old = NEG_BIG, l_old = 0.f;        // stats for q=16wp+c, this quarter
        f32x4 o_acc[4];
#pragma unroll
        for (int n = 0; n < 4; ++n) o_acc[n] = (f32x4){0.f, 0.f, 0.f, 0.f};

        // K tile 32 KB / 16 waves = 2 KB each
        auto STAGE_K = [&](int kt) {
#pragma unroll
            for (int i = 0; i < 2; ++i) {
                const int off = w * 2048 + i * 1024;
                const int ba  = off + lane * 16;
                const int row = ba >> 7;
                const int slot = (ba & 127) >> 4;
                gload16(Kg + (kt * 256 + row) * 64 + ((slot ^ (row & 7)) * 8),
                        (char*)&Kbuf[0] + off);
            }
        };
        auto STAGE_V = [&](int kt, int vb) {
#pragma unroll
            for (int i = 0; i < 2; ++i) {
                const int off = w * 2048 + i * 1024;
                const int ba  = off + lane * 16;
                const int dd  = ba >> 9;
                const int slot = (ba & 511) >> 4;
                gload16(Vg + dd * TOTAL + kt * 256 + ((slot ^ (dd & 7)) * 8),
                        (char*)&Vbuf[vb][0] + off);
            }
        };

        if (phase) __syncthreads();    // prior phase's merge reads retired before restage
        STAGE_K(kt0);
        STAGE_V(kt0, cur);

        for (int kt = kt0; kt < nkt; ++kt) {
            __syncthreads();           // barA: K(kt), V[cur] staged

            // QK over this wave's 64 keys: s_acc[n][r] = S[q=16wp+c][k=koff+16n+4g+r]
            f32x4 s_acc[4];
#pragma unroll
            for (int n = 0; n < 4; ++n) {
                const int row = koff + 16 * n + c;
                const bf16x8 kb0 = *(const bf16x8*)&Kbuf[row * 64 + ((g + 0) ^ c7) * 8];
                const bf16x8 kb1 = *(const bf16x8*)&Kbuf[row * 64 + ((g + 4) ^ c7) * 8];
                f32x4 a = __builtin_amdgcn_mfma_f32_16x16x32_bf16(kb0, qa0, (f32x4){0.f,0.f,0.f,0.f}, 0, 0, 0);
                s_acc[n] = __builtin_amdgcn_mfma_f32_16x16x32_bf16(kb1, qa1, a, 0, 0, 0);
            }
            __syncthreads();           // barB: all QK LDS reads retired -> K free
            if (kt + 1 < nkt) STAGE_K(kt + 1);

            // softmax (exp2-domain, defer-max THR=8) over 16 in-reg values
            f32x4 m4 = s_acc[0];
#pragma unroll
            for (int n = 1; n < 4; ++n)
#pragma unroll
                for (int r = 0; r < 4; ++r) m4[r] = fmaxf(m4[r], s_acc[n][r]);
            float tm = fmaxf(fmaxf(m4[0], m4[1]), fmaxf(m4[2], m4[3])) * LOG2E_8;
            tm = fmaxf(tm, __shfl_xor(tm, 16));
            tm = fmaxf(tm, __shfl_xor(tm, 32));
            if (!__all(tm <= m_old + 8.0f)) {
                const float m_new = fmaxf(m_old, tm);
                const float corr = exp2f(m_old - m_new);
                float corr_r[4];
#pragma unroll
                for (int r = 0; r < 4; ++r) corr_r[r] = __shfl(corr, 4 * g + r);
#pragma unroll
                for (int n = 0; n < 4; ++n)
#pragma unroll
                    for (int r = 0; r < 4; ++r) o_acc[n][r] *= corr_r[r];
                l_old *= corr;
                m_old = m_new;
            }
            float rs = 0.f;
#pragma unroll
            for (int n = 0; n < 4; ++n)
#pragma unroll
                for (int r = 0; r < 4; ++r) {
                    const float pv = exp2f(fmaf(s_acc[n][r], LOG2E_8, -m_old));
                    s_acc[n][r] = pv;
                    rs += pv;
                }
            rs += __shfl_xor(rs, 16);
            rs += __shfl_xor(rs, 32);
            l_old += rs;

            // P write (wave-local rows, own key-quarter columns)
#pragma unroll
            for (int n = 0; n < 4; ++n) {
                ushort4v pk;
#pragma unroll
                for (int r = 0; r < 4; ++r) pk[r] = f2bf(s_acc[n][r]);
                *(ushort4v*)&P_lds[16 * wp + c][koff + 16 * n + 4 * g] = pk;
            }

            if (kt + 1 < nkt) STAGE_V(kt + 1, cur ^ 1);   // overlap with PV

            // PV over this wave's quarter (2 k-slices of 32)
#pragma unroll
            for (int kk = 0; kk < 2; ++kk) {
                const bf16x8 pa = *(const bf16x8*)&P_lds[16 * wp + c][koff + 8 * g + 32 * kk];
                const int vgrp = (qu * 8 + 4 * kk + g) ^ c7;
#pragma unroll
                for (int n = 0; n < 4; ++n) {
                    const bf16x8 vb = *(const bf16x8*)&Vbuf[cur][(16 * n + c) * 256 + vgrp * 8];
                    o_acc[n] = __builtin_amdgcn_mfma_f32_16x16x32_bf16(pa, vb, o_acc[n], 0, 0, 0);
                }
            }
            cur ^= 1;
        }

        // ---- 4-way merge of key quarters (Vbuf reused as f32 scratch) ----
        __syncthreads();               // all PV reads retired -> Vbuf free
        float* scr = (float*)&Vbuf[0][0];   // 3 x [64][64] f32 = 48 KB
        if (qu != 0) {
            float* s0 = scr + (qu - 1) * 4096;
#pragma unroll
            for (int n = 0; n < 4; ++n)
#pragma unroll
                for (int r = 0; r < 4; ++r)
                    s0[(16 * wp + 4 * g + r) * 64 + 16 * n + c] = o_acc[n][r];
            if (g == 0) Oml[qu - 1][16 * wp + c] = make_float2(m_old, l_old);
        }
        __syncthreads();
        if (qu == 0) {
            const int row = 16 * wp + c;
            const float2 q1 = Oml[0][row];
            const float2 q2 = Oml[1][row];
            const float2 q3 = Oml[2][row];
            const float mm = fmaxf(fmaxf(m_old, q1.x), fmaxf(q2.x, q3.x));
            const float f0 = exp2f(m_old - mm), f1 = exp2f(q1.x - mm);
            const float f2 = exp2f(q2.x - mm), f3 = exp2f(q3.x - mm);
            float l = l_old * f0 + q1.y * f1 + q2.y * f2 + q3.y * f3;
            float so = 1.f;
            if (extra > 0.f) {
                const float mn = fmaxf(mm, 0.f);
                const float cc = exp2f(mm - mn);
                l = l * cc + extra * exp2f(-mn);
                so = cc;
            }
            const float inv = so / l;
            const float a0 = f0 * inv, a1 = f1 * inv, a2 = f2 * inv, a3 = f3 * inv;
            float a0r[4], a1r[4], a2r[4], a3r[4];
#pragma unroll
            for (int r = 0; r < 4; ++r) {
                a0r[r] = __shfl(a0, 4 * g + r);
                a1r[r] = __shfl(a1, 4 * g + r);
                a2r[r] = __shfl(a2, 4 * g + r);
                a3r[r] = __shfl(a3, 4 * g + r);
            }
            unsigned short* yb = y + (base + qt * 64 + 16 * wp) * 512 + h * 64;
#pragma unroll
            for (int n = 0; n < 4; ++n)
#pragma unroll
                for (int r = 0; r < 4; ++r) {
                    const int ro = (16 * wp + 4 * g + r) * 64 + 16 * n + c;
                    float o = o_acc[n][r] * a0r[r];
                    o += scr[ro] * a1r[r];
                    o += scr[4096 + ro] * a2r[r];
                    o += scr[8192 + ro] * a3r[r];
                    yb[(4 * g + r) * 512 + 16 * n + c] = f2bf(o);
                }
        }
    }
}

// ---------------- output projection: bf16 MFMA, 64x64 tile (proven) -----------
__global__ __launch_bounds__(256) void proj_mfma_kernel(
    const unsigned short* __restrict__ A,    // y_bf [2560][512]
    const unsigned short* __restrict__ Bm,   // projw_bf [512][512]
    const float* __restrict__ bias,
    float* __restrict__ out)
{
    __shared__ unsigned short Abuf[2][64 * 64];
    __shared__ unsigned short Bbuf[2][64 * 64];
    const int m0 = blockIdx.x * 64;
    const int n0 = blockIdx.y * 64;
    const int t = threadIdx.x;
    const int w = t >> 6, lane = t & 63;
    const int wr = w >> 1, wc = w & 1;
    const int c = lane & 15, g = lane >> 4;

    auto STAGE = [&](int kt, int cur) {
#pragma unroll
        for (int i = 0; i < 2; ++i) {
            const int off = w * 2048 + i * 1024;
            const int ba  = off + lane * 16;
            const int row = ba >> 7;
            const int slot = (ba & 127) >> 4;
            gload16(A  + (m0 + row) * 512 + kt * 64 + ((slot ^ (row & 7)) * 8),
                    (char*)&Abuf[cur][0] + off);
            gload16(Bm + (n0 + row) * 512 + kt * 64 + ((slot ^ (row & 7)) * 8),
                    (char*)&Bbuf[cur][0] + off);
        }
    };

    f32x4 acc[2][2];
#pragma unroll
    for (int mi = 0; mi < 2; ++mi)
#pragma unroll
        for (int ni = 0; ni < 2; ++ni) acc[mi][ni] = (f32x4){0.f, 0.f, 0.f, 0.f};

    STAGE(0, 0);
    int cur = 0;
    for (int kt = 0; kt < 8; ++kt) {
        __syncthreads();
        if (kt + 1 < 8) STAGE(kt + 1, cur ^ 1);
#pragma unroll
        for (int kk = 0; kk < 2; ++kk) {
            bf16x8 af[2], bfr[2];
#pragma unroll
            for (int mi = 0; mi < 2; ++mi) {
                const int row = wr * 32 + mi * 16 + c;
                af[mi] = *(const bf16x8*)&Abuf[cur][row * 64 + ((g + 4 * kk) ^ (row & 7)) * 8];
            }
#pragma unroll
            for (int ni = 0; ni < 2; ++ni) {
                const int row = wc * 32 + ni * 16 + c;
                bfr[ni] = *(const bf16x8*)&Bbuf[cur][row * 64 + ((g + 4 * kk) ^ (row & 7)) * 8];
            }
#pragma unroll
            for (int mi = 0; mi < 2; ++mi)
#pragma unroll
                for (int ni = 0; ni < 2; ++ni)
                    acc[mi][ni] = __builtin_amdgcn_mfma_f32_16x16x32_bf16(af[mi], bfr[ni], acc[mi][ni], 0, 0, 0);
        }
        cur ^= 1;
    }

#pragma unroll
    for (int mi = 0; mi < 2; ++mi)
#pragma unroll
        for (int ni = 0; ni < 2; ++ni) {
            const int col = n0 + wc * 32 + ni * 16 + c;
            const float bv = bias[col];
#pragma unroll
            for (int r = 0; r < 4; ++r) {
                const int p = m0 + wr * 32 + mi * 16 + 4 * g + r;
                out[p * 512 + col] = acc[mi][ni][r] + bv;
            }
        }
}

extern "C" void kernel_launch(void* const* d_in, const int* in_sizes, int n_in,
                              void* d_out, int out_size, void* d_ws, size_t ws_size,
                              hipStream_t stream) {
    const float* features = (const float*)d_in[0];
    const float* coords   = (const float*)d_in[1];
    const float* qkv_w    = (const float*)d_in[2];
    const float* proj_w   = (const float*)d_in[3];
    const float* proj_b   = (const float*)d_in[4];
    const float* pos_w    = (const float*)d_in[5];
    const float* pos_b    = (const float*)d_in[6];
    float* out = (float*)d_out;

    float* pos_ws = (float*)d_ws;                                    // 163840 f32
    unsigned short* feat_bf  = (unsigned short*)(pos_ws + TOTAL * 64);
    unsigned short* qkvw_bf  = feat_bf + 2560 * 512;
    unsigned short* projw_bf = qkvw_bf + 1536 * 512;
    unsigned short* q_ws  = projw_bf + 512 * 512;
    unsigned short* k_ws  = q_ws  + 8 * TOTAL * 64;
    unsigned short* vt_ws = k_ws  + 8 * TOTAL * 64;
    unsigned short* y_bf  = vt_ws + 8 * TOTAL * 64;                  // 2560*512 bf16

    pos_cast_kernel<<<dim3(1792), dim3(256), 0, stream>>>(
        coords, pos_w, pos_b, features, qkv_w, proj_w,
        pos_ws, feat_bf, qkvw_bf, projw_bf);
    qkv_mfma_kernel<<<dim3(40, 24), dim3(256), 0, stream>>>(
        feat_bf, qkvw_bf, pos_ws, q_ws, k_ws, vt_ws);
    attn_kernel<<<dim3(256), dim3(1024), 0, stream>>>(q_ws, k_ws, vt_ws, y_bf);
    proj_mfma_kernel<<<dim3(40, 8), dim3(256), 0, stream>>>(
        y_bf, projw_bf, proj_b, out);
}